// Round 3
// baseline (675.883 us; speedup 1.0000x reference)
//
#include <hip/hip_runtime.h>

// ---------------------------------------------------------------------------
// AttentionLayer (SAGAN-style) on MI355X, bf16 MFMA pipeline.
// Shapes: B=8, Cin=512, C=256, Cr=64, H=W=48, N=2304.
// Pipeline: fold BN -> transpose x -> convert weights -> conv_pre(MFMA,bf16)
//           -> qkv(MFMA) -> flash attention (MFMA, online softmax)
//           -> conv_f(MFMA) -> d_out (f32).
// R2 fix: qkv_mfma wt staging copied 4 uint4 per thread instead of 8.
// R3 fix: flash_mfma PV computed/wrote only channels 0..63 (all 4 waves did
//         the same slice); wave wv now owns channel block wv*64. Channels
//         64..255 of ofT were previously left 0xAA-poisoned -> conv_f saw
//         ~zeros for 3/4 of its input (absmax ~4.7, full output scale).
// ---------------------------------------------------------------------------

typedef __attribute__((ext_vector_type(8))) short short8;   // 8 x bf16 (4 VGPR)
typedef __attribute__((ext_vector_type(4))) float f32x4;    // MFMA accumulator

#define MFMA16(A,B,C) __builtin_amdgcn_mfma_f32_16x16x32_bf16((A),(B),(C),0,0,0)

#define NB   8
#define CIN  512
#define CC   256
#define NPIX 2304
#define HWD  48
#define EPSF 1e-5f

typedef unsigned short u16;
typedef unsigned int   u32;

__device__ __forceinline__ u16 f2bf(float f) {
  union { float f; u32 u; } v; v.f = f;
  u32 r = v.u + 0x7FFFu + ((v.u >> 16) & 1u);   // round-to-nearest-even
  return (u16)(r >> 16);
}
__device__ __forceinline__ float bf2f(u16 h) {
  union { u32 u; float f; } v; v.u = ((u32)h) << 16; return v.f;
}

// ---------------------------------------------------------------------------
// K0: fold BN (+conv bias) into per-channel scale/shift.
// fold[0..255]=scale1, [256..511]=shift1, [512..767]=scale2, [768..1023]=shift2
// ---------------------------------------------------------------------------
__global__ void fold_bn(const float* __restrict__ b_pre,
                        const float* __restrict__ g1, const float* __restrict__ bb1,
                        const float* __restrict__ m1, const float* __restrict__ v1,
                        const float* __restrict__ b_f,
                        const float* __restrict__ g2, const float* __restrict__ bb2,
                        const float* __restrict__ m2, const float* __restrict__ v2,
                        float* __restrict__ fold) {
  int c = threadIdx.x;
  if (c < CC) {
    float inv1 = g1[c] / sqrtf(v1[c] + EPSF);
    fold[c]        = inv1;
    fold[CC + c]   = (b_pre[c] - m1[c]) * inv1 + bb1[c];
    float inv2 = g2[c] / sqrtf(v2[c] + EPSF);
    fold[2*CC + c] = inv2;
    fold[3*CC + c] = (b_f[c] - m2[c]) * inv2 + bb2[c];
  }
}

// ---------------------------------------------------------------------------
// K0b: transpose x [b][512][2304] f32 -> xT bf16 [b][2304][512]
// ---------------------------------------------------------------------------
__launch_bounds__(256)
__global__ void transpose_x(const float* __restrict__ x, u16* __restrict__ xT) {
  __shared__ u16 t[32][33];
  int tid = threadIdx.x;
  int n0 = blockIdx.x * 32, c0 = blockIdx.y * 32, b = blockIdx.z;
#pragma unroll
  for (int it = 0; it < 4; ++it) {
    int cc = (tid >> 5) + it * 8;
    int nn = tid & 31;
    t[nn][cc] = f2bf(x[((size_t)(b * CIN + c0 + cc)) * NPIX + n0 + nn]);
  }
  __syncthreads();
#pragma unroll
  for (int it = 0; it < 2; ++it) {
    int nn = (tid >> 4) + it * 16;
    int cc2 = (tid & 15) * 2;
    u32 o = (u32)t[nn][cc2] | ((u32)t[nn][cc2 + 1] << 16);
    *(u32*)&xT[((size_t)b * NPIX + n0 + nn) * CIN + c0 + cc2] = o;
  }
}

// ---------------------------------------------------------------------------
// K0c: convert/relayout weights to bf16.
//  wbpre[9][256][512] <- w_pre[co][ci][tap] ; wbf[9][256][256] <- w_f
//  wqb[64][256], wkb[64][256], wvb[256][256] <- direct cast
// ---------------------------------------------------------------------------
__launch_bounds__(256)
__global__ void conv_w(const float* __restrict__ wpre, const float* __restrict__ wf,
                       const float* __restrict__ wq, const float* __restrict__ wk,
                       const float* __restrict__ wvw,
                       u16* __restrict__ wbpre, u16* __restrict__ wbf,
                       u16* __restrict__ wqb, u16* __restrict__ wkb,
                       u16* __restrict__ wvb) {
  int idx = blockIdx.x * 256 + threadIdx.x;
  if (idx < 1179648) {                       // 9*256*512
    int tap = idx / 131072, rem = idx % 131072;
    int co = rem >> 9, ci = rem & 511;
    wbpre[idx] = f2bf(wpre[((size_t)co * CIN + ci) * 9 + tap]);
  } else if (idx < 1769472) {                // + 9*256*256
    int j = idx - 1179648;
    int tap = j / 65536, rem = j % 65536;
    int co = rem >> 8, ci = rem & 255;
    wbf[j] = f2bf(wf[((size_t)co * CC + ci) * 9 + tap]);
  } else if (idx < 1785856) {                // + 64*256
    int j = idx - 1769472; wqb[j] = f2bf(wq[j]);
  } else if (idx < 1802240) {                // + 64*256
    int j = idx - 1785856; wkb[j] = f2bf(wk[j]);
  } else if (idx < 1867776) {                // + 256*256
    int j = idx - 1802240; wvb[j] = f2bf(wvw[j]);
  }
}

// ---------------------------------------------------------------------------
// conv3x3 (pad 1) + BN + ReLU via implicit-GEMM MFMA.
//  inT: bf16 [b][2304][CINT] (pixel-major).  wb: bf16 [9][256][CINT].
//  Block: one h-row (48 px) x 64 co; wave wv owns co sub-tile wv*16.
//  K-loop: ci chunks of 32 x 9 taps.
//  TOUT=true : D^T -> outB bf16 [b][2304][256]   (conv_pre -> x1T)
//  TOUT=false: D   -> outF f32  [b][256][2304]   (conv_f  -> d_out)
// ---------------------------------------------------------------------------
template<int CINT, bool TOUT>
__launch_bounds__(256)
__global__ void conv_mfma(const u16* __restrict__ inT, const u16* __restrict__ wb,
                          const float* __restrict__ scale, const float* __restrict__ shift,
                          u16* __restrict__ outB, float* __restrict__ outF) {
  __shared__ u16 xs[150 * 40];    // [3 rows][50 cols][ci32 pad->40]
  __shared__ u16 wsl[576 * 40];   // [9 taps][64 co][ci32 pad->40]
  int tid = threadIdx.x;
  int lane = tid & 63, wv = tid >> 6;
  int l15 = lane & 15, g = lane >> 4;
  int h = blockIdx.x, cob = blockIdx.y * 64, b = blockIdx.z;

  f32x4 z4 = {0.f, 0.f, 0.f, 0.f};
  f32x4 acc[3] = {z4, z4, z4};

#pragma unroll 1
  for (int ci0 = 0; ci0 < CINT; ci0 += 32) {
    __syncthreads();
    // stage xs: rows h-1..h+1, cols -1..48 (stored +1), 32 ci each (64B)
    if (tid < 150) {
      int rr = tid / 50, col = tid % 50 - 1;
      int hh = h - 1 + rr;
      uint4 v0 = {0,0,0,0}, v1 = v0, v2 = v0, v3 = v0;
      if ((unsigned)hh < 48u && (unsigned)col < 48u) {
        const uint4* src = (const uint4*)&inT[((size_t)b * NPIX + hh * HWD + col) * CINT + ci0];
        v0 = src[0]; v1 = src[1]; v2 = src[2]; v3 = src[3];
      }
      uint4* dst = (uint4*)&xs[tid * 40];
      dst[0] = v0; dst[1] = v1; dst[2] = v2; dst[3] = v3;
    }
    // stage wsl: 576 rows x 64B
#pragma unroll
    for (int it = 0; it < 9; ++it) {
      int slot = tid + it * 256;
      int row = slot >> 2, q4 = slot & 3;
      int tap = row >> 6, co = row & 63;
      *((uint4*)&wsl[row * 40] + q4) =
          *(const uint4*)&wb[((size_t)(tap * 256 + cob + co)) * CINT + ci0 + q4 * 8];
    }
    __syncthreads();
#pragma unroll
    for (int kh = 0; kh < 3; ++kh) {
#pragma unroll
      for (int kw = 0; kw < 3; ++kw) {
        int tap = kh * 3 + kw;
        short8 wf = *(const short8*)&wsl[((tap * 64) + wv * 16 + l15) * 40 + g * 8];
#pragma unroll
        for (int t = 0; t < 3; ++t) {
          short8 xf = *(const short8*)&xs[(kh * 50 + t * 16 + l15 + kw) * 40 + g * 8];
          if constexpr (TOUT) acc[t] = MFMA16(xf, wf, acc[t]);   // D^T[px][co]
          else                acc[t] = MFMA16(wf, xf, acc[t]);   // D[co][px]
        }
      }
    }
  }

  if constexpr (TOUT) {
    int co = cob + wv * 16 + l15;
    float sc = scale[co], sh = shift[co];
#pragma unroll
    for (int t = 0; t < 3; ++t)
#pragma unroll
      for (int r = 0; r < 4; ++r) {
        int px = h * HWD + t * 16 + 4 * g + r;
        float v = fmaxf(fmaf(acc[t][r], sc, sh), 0.f);
        outB[((size_t)b * NPIX + px) * CC + co] = f2bf(v);
      }
  } else {
#pragma unroll
    for (int r = 0; r < 4; ++r) {
      int co = cob + wv * 16 + 4 * g + r;
      float sc = scale[co], sh = shift[co];
#pragma unroll
      for (int t = 0; t < 3; ++t) {
        int px = h * HWD + t * 16 + l15;
        float v = fmaxf(fmaf(acc[t][r], sc, sh), 0.f);
        outF[((size_t)b * CC + co) * NPIX + px] = v;
      }
    }
  }
}

// ---------------------------------------------------------------------------
// qkv 1x1 convs via MFMA. x1T bf16 [b][2304][256].
//  y=0: q -> qb [b][2304][64]   (D^T)
//  y=1: k -> kb [b][2304][64]   (D^T)
//  y=2..5: v (m tile 64 each) -> vb [b][256][2304]  (D)
// ---------------------------------------------------------------------------
__launch_bounds__(256)
__global__ void qkv_mfma(const u16* __restrict__ x1T,
                         const u16* __restrict__ wqb, const u16* __restrict__ wkb,
                         const u16* __restrict__ wvb,
                         const float* __restrict__ b_q, const float* __restrict__ b_k,
                         const float* __restrict__ b_v,
                         u16* __restrict__ qb, u16* __restrict__ kb,
                         u16* __restrict__ vb) {
  __shared__ u16 xt[32 * 264];   // [n 32][c 256 pad->264]
  __shared__ u16 wt[64 * 264];   // [m 64][c 256 pad->264]
  int tid = threadIdx.x;
  int lane = tid & 63, wv = tid >> 6;
  int l15 = lane & 15, g = lane >> 4;
  int n0 = blockIdx.x * 32, y = blockIdx.y, b = blockIdx.z;
  const u16* w; const float* bias; int mb = 0;
  if (y == 0)      { w = wqb; bias = b_q; }
  else if (y == 1) { w = wkb; bias = b_k; }
  else             { w = wvb; bias = b_v; mb = (y - 2) * 64; }
  {
    int row = tid >> 3, s = (tid & 7) * 32;
    const uint4* src = (const uint4*)&x1T[((size_t)b * NPIX + n0 + row) * CC + s];
    uint4* dst = (uint4*)&xt[row * 264 + s];
    dst[0] = src[0]; dst[1] = src[1]; dst[2] = src[2]; dst[3] = src[3];
  }
  {
    int row = tid >> 2, s = (tid & 3) * 64;   // 64 u16 = 8 uint4 per thread
    const uint4* src = (const uint4*)&w[((size_t)(mb + row)) * CC + s];
    uint4* dst = (uint4*)&wt[row * 264 + s];
#pragma unroll
    for (int u = 0; u < 8; ++u) dst[u] = src[u];
  }
  __syncthreads();
  f32x4 z4 = {0.f, 0.f, 0.f, 0.f};
  f32x4 acc[2] = {z4, z4};
  if (y <= 1) {
#pragma unroll
    for (int cc = 0; cc < 8; ++cc) {
      short8 wf = *(const short8*)&wt[(wv * 16 + l15) * 264 + cc * 32 + g * 8];
#pragma unroll
      for (int nt = 0; nt < 2; ++nt) {
        short8 xf = *(const short8*)&xt[(nt * 16 + l15) * 264 + cc * 32 + g * 8];
        acc[nt] = MFMA16(xf, wf, acc[nt]);    // D^T[n][m]
      }
    }
    u16* outp = (y == 0) ? qb : kb;
    int m = wv * 16 + l15;
    float bi = bias[m];
#pragma unroll
    for (int nt = 0; nt < 2; ++nt)
#pragma unroll
      for (int r = 0; r < 4; ++r) {
        int n = n0 + nt * 16 + 4 * g + r;
        outp[((size_t)b * NPIX + n) * 64 + m] = f2bf(acc[nt][r] + bi);
      }
  } else {
#pragma unroll
    for (int cc = 0; cc < 8; ++cc) {
      short8 wf = *(const short8*)&wt[(wv * 16 + l15) * 264 + cc * 32 + g * 8];
#pragma unroll
      for (int nt = 0; nt < 2; ++nt) {
        short8 xf = *(const short8*)&xt[(nt * 16 + l15) * 264 + cc * 32 + g * 8];
        acc[nt] = MFMA16(wf, xf, acc[nt]);    // D[m][n]
      }
    }
    int mrow = mb + wv * 16 + 4 * g;
#pragma unroll
    for (int r = 0; r < 4; ++r) {
      float bi = bias[mrow + r];
#pragma unroll
      for (int nt = 0; nt < 2; ++nt) {
        int n = n0 + nt * 16 + l15;
        vb[((size_t)b * CC + mrow + r) * NPIX + n] = f2bf(acc[nt][r] + bi);
      }
    }
  }
}

// ---------------------------------------------------------------------------
// Flash attention (unscaled energies, softmax over j) + residual.
//  qb/kb bf16 [b][n][64]; vb bf16 [b][256][n]; x1T bf16 [b][n][256].
//  Block: 32 i-rows, 4 waves. QK^T + softmax duplicated per wave (cheap);
//  each wave owns channel block wv*64 for PV/epilogue. Swapped QK^T -> S^T
//  so softmax state is lane-local (i=l15). Swapped PV -> out^T[c][i];
//  epilogue writes ofT bf16 [b][n][256] (gamma*out/d + x1 residual).
// ---------------------------------------------------------------------------
__launch_bounds__(256)
__global__ void flash_mfma(const u16* __restrict__ qbp, const u16* __restrict__ kbp,
                           const u16* __restrict__ vbp, const u16* __restrict__ x1T,
                           const float* __restrict__ gamma, u16* __restrict__ ofT) {
  __shared__ u16 qsb[32 * 72];    // [i 32][c 64 pad->72]
  __shared__ u16 ksb[32 * 72];    // [j 32][c 64 pad->72]
  __shared__ u16 vtb[256 * 40];   // [c 256][j 32 pad->40]
  __shared__ u16 pbuf[32 * 40];   // [i 32][j 32 pad->40] bf16 P
  int tid = threadIdx.x;
  int lane = tid & 63, wv = tid >> 6;
  int l15 = lane & 15, g = lane >> 4;
  int i0 = blockIdx.x * 32, b = blockIdx.y;
  {
    int row = tid >> 3, s8 = (tid & 7) * 8;
    *(uint4*)&qsb[row * 72 + s8] =
        *(const uint4*)&qbp[((size_t)b * NPIX + i0 + row) * 64 + s8];
  }
  __syncthreads();
  short8 qf[2][2];
#pragma unroll
  for (int it = 0; it < 2; ++it)
#pragma unroll
    for (int cc = 0; cc < 2; ++cc)
      qf[it][cc] = *(const short8*)&qsb[(it * 16 + l15) * 72 + cc * 32 + g * 8];

  f32x4 z4 = {0.f, 0.f, 0.f, 0.f};
  f32x4 acc[4][2];
#pragma unroll
  for (int ct = 0; ct < 4; ++ct) { acc[ct][0] = z4; acc[ct][1] = z4; }
  float m_r[2] = {-1e30f, -1e30f};
  float d_r[2] = {0.f, 0.f};

#pragma unroll 1
  for (int jt = 0; jt < 72; ++jt) {
    int j0 = jt * 32;
    __syncthreads();   // prev-tile PV reads of vtb/pbuf done
    {
      int row = tid >> 3, s8 = (tid & 7) * 8;
      *(uint4*)&ksb[row * 72 + s8] =
          *(const uint4*)&kbp[((size_t)b * NPIX + j0 + row) * 64 + s8];
    }
    {
      int c = tid;
      const uint4* src = (const uint4*)&vbp[((size_t)b * CC + c) * NPIX + j0];
      uint4 arr[4];
      arr[0] = src[0]; arr[1] = src[1]; arr[2] = src[2]; arr[3] = src[3];
      uint4* dst = (uint4*)&vtb[c * 40];
      int us = (c >> 3) & 3;
#pragma unroll
      for (int u = 0; u < 4; ++u) { int uu = (u + us) & 3; dst[uu] = arr[uu]; }
    }
    __syncthreads();
    // QK^T (swapped): S^T[j = jh*16+4g+r][i = it*16+l15]
    f32x4 s[2][2];
#pragma unroll
    for (int jh = 0; jh < 2; ++jh) {
      short8 kf0 = *(const short8*)&ksb[(jh * 16 + l15) * 72 + 0 + g * 8];
      short8 kf1 = *(const short8*)&ksb[(jh * 16 + l15) * 72 + 32 + g * 8];
#pragma unroll
      for (int it = 0; it < 2; ++it) {
        s[jh][it] = MFMA16(kf0, qf[it][0], z4);
        s[jh][it] = MFMA16(kf1, qf[it][1], s[jh][it]);
      }
    }
    // online softmax per i (lane-local, reduce over j = regs + lanes 16/32)
#pragma unroll
    for (int it = 0; it < 2; ++it) {
      float mx = s[0][it][0];
#pragma unroll
      for (int r = 1; r < 4; ++r) mx = fmaxf(mx, s[0][it][r]);
#pragma unroll
      for (int r = 0; r < 4; ++r) mx = fmaxf(mx, s[1][it][r]);
      mx = fmaxf(mx, __shfl_xor(mx, 16));
      mx = fmaxf(mx, __shfl_xor(mx, 32));
      float mold = m_r[it];
      float mnew = fmaxf(mold, mx);
      float scl = __expf(mold - mnew);
      float pj[2][4];
      float sum = 0.f;
#pragma unroll
      for (int jh = 0; jh < 2; ++jh)
#pragma unroll
        for (int r = 0; r < 4; ++r) {
          float p = __expf(s[jh][it][r] - mnew);
          pj[jh][r] = p; sum += p;
        }
      sum += __shfl_xor(sum, 16);
      sum += __shfl_xor(sum, 32);
      d_r[it] = d_r[it] * scl + sum;
      m_r[it] = mnew;
#pragma unroll
      for (int ct = 0; ct < 4; ++ct) acc[ct][it] = acc[ct][it] * scl;
      if ((wv >> 1) == it) {         // this wave writes quadrant (it, jh=wv&1)
        int jh = wv & 1;
#pragma unroll
        for (int r = 0; r < 4; ++r)
          pbuf[(it * 16 + l15) * 40 + jh * 16 + 4 * g + r] = f2bf(pj[jh][r]);
      }
    }
    __syncthreads();   // pbuf ready
    // PV (swapped): out^T[c][i] += V^T x P^T , K = j (32).
    // Wave wv owns channel block wv*64 (R3 fix).
    short8 pf0 = *(const short8*)&pbuf[(l15) * 40 + g * 8];
    short8 pf1 = *(const short8*)&pbuf[(16 + l15) * 40 + g * 8];
#pragma unroll
    for (int ct = 0; ct < 4; ++ct) {
      short8 vf = *(const short8*)&vtb[(wv * 64 + ct * 16 + l15) * 40 + g * 8];
      acc[ct][0] = MFMA16(vf, pf0, acc[ct][0]);
      acc[ct][1] = MFMA16(vf, pf1, acc[ct][1]);
    }
  }
  // epilogue: ofT[i][c] = gamma * out/d + x1   (wave wv -> channels wv*64+..)
  float gm = gamma[0];
#pragma unroll
  for (int it = 0; it < 2; ++it) {
    float invd = 1.f / d_r[it];
    int i = i0 + it * 16 + l15;
#pragma unroll
    for (int ct = 0; ct < 4; ++ct)
#pragma unroll
      for (int r = 0; r < 4; ++r) {
        int c = wv * 64 + ct * 16 + 4 * g + r;
        size_t idx = ((size_t)b * NPIX + i) * CC + c;
        ofT[idx] = f2bf(gm * acc[ct][it][r] * invd + bf2f(x1T[idx]));
      }
  }
}

// ---------------------------------------------------------------------------
// Host launcher. Workspace layout (u16 elements unless noted):
//  xT 9437184 | x1T 4718592 | qb 1179648 | kb 1179648 | vb 4718592 |
//  ofT 4718592 | wbpre 1179648 | wbf 589824 | wqb 16384 | wkb 16384 |
//  wvb 65536 | fold (f32[1024])            total ~55.6 MB
// ---------------------------------------------------------------------------
extern "C" void kernel_launch(void* const* d_in, const int* in_sizes, int n_in,
                              void* d_out, int out_size, void* d_ws, size_t ws_size,
                              hipStream_t stream) {
  (void)in_sizes; (void)n_in; (void)out_size; (void)ws_size;
  const float* x     = (const float*)d_in[0];
  const float* w_pre = (const float*)d_in[1];
  const float* b_pre = (const float*)d_in[2];
  const float* bn1_g = (const float*)d_in[3];
  const float* bn1_b = (const float*)d_in[4];
  const float* bn1_m = (const float*)d_in[5];
  const float* bn1_v = (const float*)d_in[6];
  const float* w_q   = (const float*)d_in[7];
  const float* b_q   = (const float*)d_in[8];
  const float* w_k   = (const float*)d_in[9];
  const float* b_k   = (const float*)d_in[10];
  const float* w_v   = (const float*)d_in[11];
  const float* b_v   = (const float*)d_in[12];
  const float* w_f   = (const float*)d_in[13];
  const float* b_f   = (const float*)d_in[14];
  const float* bn2_g = (const float*)d_in[15];
  const float* bn2_b = (const float*)d_in[16];
  const float* bn2_m = (const float*)d_in[17];
  const float* bn2_v = (const float*)d_in[18];
  const float* gamma = (const float*)d_in[19];
  float* out = (float*)d_out;

  u16* wsu   = (u16*)d_ws;
  u16* xT    = wsu;
  u16* x1T   = wsu + 9437184;
  u16* qb    = wsu + 14155776;
  u16* kb    = wsu + 15335424;
  u16* vb    = wsu + 16515072;
  u16* ofT   = wsu + 21233664;
  u16* wbpre = wsu + 25952256;
  u16* wbf   = wsu + 27131904;
  u16* wqb   = wsu + 27721728;
  u16* wkb   = wsu + 27738112;
  u16* wvb   = wsu + 27754496;
  float* fold = (float*)(wsu + 27820032);

  fold_bn<<<1, 256, 0, stream>>>(b_pre, bn1_g, bn1_b, bn1_m, bn1_v,
                                 b_f, bn2_g, bn2_b, bn2_m, bn2_v, fold);
  transpose_x<<<dim3(72, 16, 8), 256, 0, stream>>>(x, xT);
  conv_w<<<7296, 256, 0, stream>>>(w_pre, w_f, w_q, w_k, w_v,
                                   wbpre, wbf, wqb, wkb, wvb);
  conv_mfma<512, true><<<dim3(48, 4, 8), 256, 0, stream>>>(
      xT, wbpre, fold, fold + 256, x1T, nullptr);
  qkv_mfma<<<dim3(72, 6, 8), 256, 0, stream>>>(
      x1T, wqb, wkb, wvb, b_q, b_k, b_v, qb, kb, vb);
  flash_mfma<<<dim3(72, 8, 1), 256, 0, stream>>>(qb, kb, vb, x1T, gamma, ofT);
  conv_mfma<256, false><<<dim3(48, 4, 8), 256, 0, stream>>>(
      ofT, wbf, fold + 512, fold + 768, nullptr, out);
}

// Round 4
// 512.529 us; speedup vs baseline: 1.3187x; 1.3187x over previous
//
#include <hip/hip_runtime.h>

// ---------------------------------------------------------------------------
// AttentionLayer (SAGAN-style) on MI355X, bf16 MFMA pipeline.
// Shapes: B=8, Cin=512, C=256, Cr=64, H=W=48, N=2304.
// Pipeline: fold BN -> transpose x -> convert weights -> conv_pre(MFMA,bf16)
//           -> qkv(MFMA) -> flash attention (MFMA, online softmax)
//           -> conv_f(MFMA) -> d_out (f32).
// R2 fix: qkv_mfma wt staging copied 4 uint4 per thread instead of 8.
// R3 fix: flash_mfma wave wv owns channel block wv*64 (was: all waves did ch
//         0..63, ch 64..255 left poisoned).
// R4: flash_mfma rewritten barrier-free. R3 profile: flash = 403us of 676us,
//     MfmaUtil 4.4%, VALUBusy 21%, Occ 23% -> latency-bound on 3 barriers/iter
//     at 2.25 blocks/CU. Now: K/V/Q fragments loaded directly from global
//     (16B contiguous per lane, full cache lines per instruction), P exchange
//     through a PER-WAVE private LDS buffer (DS ops in a wave complete in
//     order -> no barrier), softmax lane-local + 2 shfl_xor. Zero
//     __syncthreads in the kernel; waves free-run.
// ---------------------------------------------------------------------------

typedef __attribute__((ext_vector_type(8))) short short8;   // 8 x bf16 (4 VGPR)
typedef __attribute__((ext_vector_type(4))) float f32x4;    // MFMA accumulator

#define MFMA16(A,B,C) __builtin_amdgcn_mfma_f32_16x16x32_bf16((A),(B),(C),0,0,0)

#define NB   8
#define CIN  512
#define CC   256
#define NPIX 2304
#define HWD  48
#define EPSF 1e-5f

typedef unsigned short u16;
typedef unsigned int   u32;

__device__ __forceinline__ u16 f2bf(float f) {
  union { float f; u32 u; } v; v.f = f;
  u32 r = v.u + 0x7FFFu + ((v.u >> 16) & 1u);   // round-to-nearest-even
  return (u16)(r >> 16);
}
__device__ __forceinline__ float bf2f(u16 h) {
  union { u32 u; float f; } v; v.u = ((u32)h) << 16; return v.f;
}

// ---------------------------------------------------------------------------
// K0: fold BN (+conv bias) into per-channel scale/shift.
// fold[0..255]=scale1, [256..511]=shift1, [512..767]=scale2, [768..1023]=shift2
// ---------------------------------------------------------------------------
__global__ void fold_bn(const float* __restrict__ b_pre,
                        const float* __restrict__ g1, const float* __restrict__ bb1,
                        const float* __restrict__ m1, const float* __restrict__ v1,
                        const float* __restrict__ b_f,
                        const float* __restrict__ g2, const float* __restrict__ bb2,
                        const float* __restrict__ m2, const float* __restrict__ v2,
                        float* __restrict__ fold) {
  int c = threadIdx.x;
  if (c < CC) {
    float inv1 = g1[c] / sqrtf(v1[c] + EPSF);
    fold[c]        = inv1;
    fold[CC + c]   = (b_pre[c] - m1[c]) * inv1 + bb1[c];
    float inv2 = g2[c] / sqrtf(v2[c] + EPSF);
    fold[2*CC + c] = inv2;
    fold[3*CC + c] = (b_f[c] - m2[c]) * inv2 + bb2[c];
  }
}

// ---------------------------------------------------------------------------
// K0b: transpose x [b][512][2304] f32 -> xT bf16 [b][2304][512]
// ---------------------------------------------------------------------------
__launch_bounds__(256)
__global__ void transpose_x(const float* __restrict__ x, u16* __restrict__ xT) {
  __shared__ u16 t[32][33];
  int tid = threadIdx.x;
  int n0 = blockIdx.x * 32, c0 = blockIdx.y * 32, b = blockIdx.z;
#pragma unroll
  for (int it = 0; it < 4; ++it) {
    int cc = (tid >> 5) + it * 8;
    int nn = tid & 31;
    t[nn][cc] = f2bf(x[((size_t)(b * CIN + c0 + cc)) * NPIX + n0 + nn]);
  }
  __syncthreads();
#pragma unroll
  for (int it = 0; it < 2; ++it) {
    int nn = (tid >> 4) + it * 16;
    int cc2 = (tid & 15) * 2;
    u32 o = (u32)t[nn][cc2] | ((u32)t[nn][cc2 + 1] << 16);
    *(u32*)&xT[((size_t)b * NPIX + n0 + nn) * CIN + c0 + cc2] = o;
  }
}

// ---------------------------------------------------------------------------
// K0c: convert/relayout weights to bf16.
//  wbpre[9][256][512] <- w_pre[co][ci][tap] ; wbf[9][256][256] <- w_f
//  wqb[64][256], wkb[64][256], wvb[256][256] <- direct cast
// ---------------------------------------------------------------------------
__launch_bounds__(256)
__global__ void conv_w(const float* __restrict__ wpre, const float* __restrict__ wf,
                       const float* __restrict__ wq, const float* __restrict__ wk,
                       const float* __restrict__ wvw,
                       u16* __restrict__ wbpre, u16* __restrict__ wbf,
                       u16* __restrict__ wqb, u16* __restrict__ wkb,
                       u16* __restrict__ wvb) {
  int idx = blockIdx.x * 256 + threadIdx.x;
  if (idx < 1179648) {                       // 9*256*512
    int tap = idx / 131072, rem = idx % 131072;
    int co = rem >> 9, ci = rem & 511;
    wbpre[idx] = f2bf(wpre[((size_t)co * CIN + ci) * 9 + tap]);
  } else if (idx < 1769472) {                // + 9*256*256
    int j = idx - 1179648;
    int tap = j / 65536, rem = j % 65536;
    int co = rem >> 8, ci = rem & 255;
    wbf[j] = f2bf(wf[((size_t)co * CC + ci) * 9 + tap]);
  } else if (idx < 1785856) {                // + 64*256
    int j = idx - 1769472; wqb[j] = f2bf(wq[j]);
  } else if (idx < 1802240) {                // + 64*256
    int j = idx - 1785856; wkb[j] = f2bf(wk[j]);
  } else if (idx < 1867776) {                // + 256*256
    int j = idx - 1802240; wvb[j] = f2bf(wvw[j]);
  }
}

// ---------------------------------------------------------------------------
// conv3x3 (pad 1) + BN + ReLU via implicit-GEMM MFMA.
//  inT: bf16 [b][2304][CINT] (pixel-major).  wb: bf16 [9][256][CINT].
//  Block: one h-row (48 px) x 64 co; wave wv owns co sub-tile wv*16.
//  K-loop: ci chunks of 32 x 9 taps.
//  TOUT=true : D^T -> outB bf16 [b][2304][256]   (conv_pre -> x1T)
//  TOUT=false: D   -> outF f32  [b][256][2304]   (conv_f  -> d_out)
// ---------------------------------------------------------------------------
template<int CINT, bool TOUT>
__launch_bounds__(256)
__global__ void conv_mfma(const u16* __restrict__ inT, const u16* __restrict__ wb,
                          const float* __restrict__ scale, const float* __restrict__ shift,
                          u16* __restrict__ outB, float* __restrict__ outF) {
  __shared__ u16 xs[150 * 40];    // [3 rows][50 cols][ci32 pad->40]
  __shared__ u16 wsl[576 * 40];   // [9 taps][64 co][ci32 pad->40]
  int tid = threadIdx.x;
  int lane = tid & 63, wv = tid >> 6;
  int l15 = lane & 15, g = lane >> 4;
  int h = blockIdx.x, cob = blockIdx.y * 64, b = blockIdx.z;

  f32x4 z4 = {0.f, 0.f, 0.f, 0.f};
  f32x4 acc[3] = {z4, z4, z4};

#pragma unroll 1
  for (int ci0 = 0; ci0 < CINT; ci0 += 32) {
    __syncthreads();
    // stage xs: rows h-1..h+1, cols -1..48 (stored +1), 32 ci each (64B)
    if (tid < 150) {
      int rr = tid / 50, col = tid % 50 - 1;
      int hh = h - 1 + rr;
      uint4 v0 = {0,0,0,0}, v1 = v0, v2 = v0, v3 = v0;
      if ((unsigned)hh < 48u && (unsigned)col < 48u) {
        const uint4* src = (const uint4*)&inT[((size_t)b * NPIX + hh * HWD + col) * CINT + ci0];
        v0 = src[0]; v1 = src[1]; v2 = src[2]; v3 = src[3];
      }
      uint4* dst = (uint4*)&xs[tid * 40];
      dst[0] = v0; dst[1] = v1; dst[2] = v2; dst[3] = v3;
    }
    // stage wsl: 576 rows x 64B
#pragma unroll
    for (int it = 0; it < 9; ++it) {
      int slot = tid + it * 256;
      int row = slot >> 2, q4 = slot & 3;
      int tap = row >> 6, co = row & 63;
      *((uint4*)&wsl[row * 40] + q4) =
          *(const uint4*)&wb[((size_t)(tap * 256 + cob + co)) * CINT + ci0 + q4 * 8];
    }
    __syncthreads();
#pragma unroll
    for (int kh = 0; kh < 3; ++kh) {
#pragma unroll
      for (int kw = 0; kw < 3; ++kw) {
        int tap = kh * 3 + kw;
        short8 wf = *(const short8*)&wsl[((tap * 64) + wv * 16 + l15) * 40 + g * 8];
#pragma unroll
        for (int t = 0; t < 3; ++t) {
          short8 xf = *(const short8*)&xs[(kh * 50 + t * 16 + l15 + kw) * 40 + g * 8];
          if constexpr (TOUT) acc[t] = MFMA16(xf, wf, acc[t]);   // D^T[px][co]
          else                acc[t] = MFMA16(wf, xf, acc[t]);   // D[co][px]
        }
      }
    }
  }

  if constexpr (TOUT) {
    int co = cob + wv * 16 + l15;
    float sc = scale[co], sh = shift[co];
#pragma unroll
    for (int t = 0; t < 3; ++t)
#pragma unroll
      for (int r = 0; r < 4; ++r) {
        int px = h * HWD + t * 16 + 4 * g + r;
        float v = fmaxf(fmaf(acc[t][r], sc, sh), 0.f);
        outB[((size_t)b * NPIX + px) * CC + co] = f2bf(v);
      }
  } else {
#pragma unroll
    for (int r = 0; r < 4; ++r) {
      int co = cob + wv * 16 + 4 * g + r;
      float sc = scale[co], sh = shift[co];
#pragma unroll
      for (int t = 0; t < 3; ++t) {
        int px = h * HWD + t * 16 + l15;
        float v = fmaxf(fmaf(acc[t][r], sc, sh), 0.f);
        outF[((size_t)b * CC + co) * NPIX + px] = v;
      }
    }
  }
}

// ---------------------------------------------------------------------------
// qkv 1x1 convs via MFMA. x1T bf16 [b][2304][256].
//  y=0: q -> qb [b][2304][64]   (D^T)
//  y=1: k -> kb [b][2304][64]   (D^T)
//  y=2..5: v (m tile 64 each) -> vb [b][256][2304]  (D)
// ---------------------------------------------------------------------------
__launch_bounds__(256)
__global__ void qkv_mfma(const u16* __restrict__ x1T,
                         const u16* __restrict__ wqb, const u16* __restrict__ wkb,
                         const u16* __restrict__ wvb,
                         const float* __restrict__ b_q, const float* __restrict__ b_k,
                         const float* __restrict__ b_v,
                         u16* __restrict__ qb, u16* __restrict__ kb,
                         u16* __restrict__ vb) {
  __shared__ u16 xt[32 * 264];   // [n 32][c 256 pad->264]
  __shared__ u16 wt[64 * 264];   // [m 64][c 256 pad->264]
  int tid = threadIdx.x;
  int lane = tid & 63, wv = tid >> 6;
  int l15 = lane & 15, g = lane >> 4;
  int n0 = blockIdx.x * 32, y = blockIdx.y, b = blockIdx.z;
  const u16* w; const float* bias; int mb = 0;
  if (y == 0)      { w = wqb; bias = b_q; }
  else if (y == 1) { w = wkb; bias = b_k; }
  else             { w = wvb; bias = b_v; mb = (y - 2) * 64; }
  {
    int row = tid >> 3, s = (tid & 7) * 32;
    const uint4* src = (const uint4*)&x1T[((size_t)b * NPIX + n0 + row) * CC + s];
    uint4* dst = (uint4*)&xt[row * 264 + s];
    dst[0] = src[0]; dst[1] = src[1]; dst[2] = src[2]; dst[3] = src[3];
  }
  {
    int row = tid >> 2, s = (tid & 3) * 64;   // 64 u16 = 8 uint4 per thread
    const uint4* src = (const uint4*)&w[((size_t)(mb + row)) * CC + s];
    uint4* dst = (uint4*)&wt[row * 264 + s];
#pragma unroll
    for (int u = 0; u < 8; ++u) dst[u] = src[u];
  }
  __syncthreads();
  f32x4 z4 = {0.f, 0.f, 0.f, 0.f};
  f32x4 acc[2] = {z4, z4};
  if (y <= 1) {
#pragma unroll
    for (int cc = 0; cc < 8; ++cc) {
      short8 wf = *(const short8*)&wt[(wv * 16 + l15) * 264 + cc * 32 + g * 8];
#pragma unroll
      for (int nt = 0; nt < 2; ++nt) {
        short8 xf = *(const short8*)&xt[(nt * 16 + l15) * 264 + cc * 32 + g * 8];
        acc[nt] = MFMA16(xf, wf, acc[nt]);    // D^T[n][m]
      }
    }
    u16* outp = (y == 0) ? qb : kb;
    int m = wv * 16 + l15;
    float bi = bias[m];
#pragma unroll
    for (int nt = 0; nt < 2; ++nt)
#pragma unroll
      for (int r = 0; r < 4; ++r) {
        int n = n0 + nt * 16 + 4 * g + r;
        outp[((size_t)b * NPIX + n) * 64 + m] = f2bf(acc[nt][r] + bi);
      }
  } else {
#pragma unroll
    for (int cc = 0; cc < 8; ++cc) {
      short8 wf = *(const short8*)&wt[(wv * 16 + l15) * 264 + cc * 32 + g * 8];
#pragma unroll
      for (int nt = 0; nt < 2; ++nt) {
        short8 xf = *(const short8*)&xt[(nt * 16 + l15) * 264 + cc * 32 + g * 8];
        acc[nt] = MFMA16(wf, xf, acc[nt]);    // D[m][n]
      }
    }
    int mrow = mb + wv * 16 + 4 * g;
#pragma unroll
    for (int r = 0; r < 4; ++r) {
      float bi = bias[mrow + r];
#pragma unroll
      for (int nt = 0; nt < 2; ++nt) {
        int n = n0 + nt * 16 + l15;
        vb[((size_t)b * CC + mrow + r) * NPIX + n] = f2bf(acc[nt][r] + bi);
      }
    }
  }
}

// ---------------------------------------------------------------------------
// Flash attention (unscaled energies, softmax over j) + residual. BARRIER-FREE.
//  qb/kb bf16 [b][n][64]; vb bf16 [b][256][n]; x1T bf16 [b][n][256].
//  Block: 32 i-rows, 4 fully independent waves. Each wave:
//   - loads Q/K/V MFMA fragments DIRECTLY from global (16B contiguous/lane;
//     one instruction touches 16 rows x 64B = whole cache lines, L1/L2-hot),
//   - computes swapped QK^T -> S^T[j][i] so softmax state is lane-local
//     (i = l15), row-reduce = 7 fmax + 2 shfl_xor,
//   - redistributes P to the PV B-fragment layout via its PRIVATE LDS slice
//     (DS ops within a wave complete in order -> no __syncthreads),
//   - swapped PV -> out^T[c][i], wave wv owns channels wv*64..wv*64+63.
//  Epilogue: ofT[i][c] = gamma*out/d + x1.
// ---------------------------------------------------------------------------
__launch_bounds__(256)
__global__ void flash_mfma(const u16* __restrict__ qbp, const u16* __restrict__ kbp,
                           const u16* __restrict__ vbp, const u16* __restrict__ x1T,
                           const float* __restrict__ gamma, u16* __restrict__ ofT) {
  __shared__ u16 pb[4][32 * 40];   // per-wave private P buffer [i 32][j 32 pad->40]
  int tid = threadIdx.x;
  int lane = tid & 63, wv = tid >> 6;
  int l15 = lane & 15, g = lane >> 4;
  int i0 = blockIdx.x * 32, b = blockIdx.y;
  u16* pbw = pb[wv];

  // Q fragments straight from global: A/B-fragment rows i = i0+it*16+l15.
  short8 qf[2][2];
#pragma unroll
  for (int it = 0; it < 2; ++it)
#pragma unroll
    for (int cc = 0; cc < 2; ++cc)
      qf[it][cc] = *(const short8*)
          &qbp[((size_t)b * NPIX + i0 + it * 16 + l15) * 64 + cc * 32 + g * 8];

  f32x4 z4 = {0.f, 0.f, 0.f, 0.f};
  f32x4 acc[4][2];
#pragma unroll
  for (int ct = 0; ct < 4; ++ct) { acc[ct][0] = z4; acc[ct][1] = z4; }
  float m_r[2] = {-1e30f, -1e30f};
  float d_r[2] = {0.f, 0.f};

  const u16* kb0 = kbp + (size_t)b * NPIX * 64;
  const u16* vb0 = vbp + ((size_t)b * CC + wv * 64) * NPIX;

#pragma unroll 1
  for (int jt = 0; jt < 72; ++jt) {
    int j0 = jt * 32;
    // K fragments: rows j = j0+jh*16+l15, 16B per lane.
    short8 kf[2][2];
#pragma unroll
    for (int jh = 0; jh < 2; ++jh)
#pragma unroll
      for (int cc = 0; cc < 2; ++cc)
        kf[jh][cc] = *(const short8*)
            &kb0[(size_t)(j0 + jh * 16 + l15) * 64 + cc * 32 + g * 8];
    // V fragments (PV A-operand): rows c = wv*64+ct*16+l15, k-cols j0+8g+e.
    short8 vf[4];
#pragma unroll
    for (int ct = 0; ct < 4; ++ct)
      vf[ct] = *(const short8*)&vb0[(size_t)(ct * 16 + l15) * NPIX + j0 + g * 8];

    // QK^T (swapped): S^T[j0+jh*16+4g+r][i0+it*16+l15]
    f32x4 s[2][2];
#pragma unroll
    for (int jh = 0; jh < 2; ++jh)
#pragma unroll
      for (int it = 0; it < 2; ++it) {
        s[jh][it] = MFMA16(kf[jh][0], qf[it][0], z4);
        s[jh][it] = MFMA16(kf[jh][1], qf[it][1], s[jh][it]);
      }

    // online softmax per i-half (lane-local; reduce over 8 regs + g-groups)
#pragma unroll
    for (int it = 0; it < 2; ++it) {
      float mx = fmaxf(fmaxf(fmaxf(s[0][it][0], s[0][it][1]),
                             fmaxf(s[0][it][2], s[0][it][3])),
                       fmaxf(fmaxf(s[1][it][0], s[1][it][1]),
                             fmaxf(s[1][it][2], s[1][it][3])));
      mx = fmaxf(mx, __shfl_xor(mx, 16));
      mx = fmaxf(mx, __shfl_xor(mx, 32));
      float mnew = fmaxf(m_r[it], mx);
      float scl = __expf(m_r[it] - mnew);
      float pj[8];
      float sum = 0.f;
#pragma unroll
      for (int jh = 0; jh < 2; ++jh)
#pragma unroll
        for (int r = 0; r < 4; ++r) {
          float p = __expf(s[jh][it][r] - mnew);
          pj[jh * 4 + r] = p; sum += p;
        }
      sum += __shfl_xor(sum, 16);
      sum += __shfl_xor(sum, 32);
      d_r[it] = d_r[it] * scl + sum;
      m_r[it] = mnew;
#pragma unroll
      for (int ct = 0; ct < 4; ++ct) acc[ct][it] = acc[ct][it] * scl;
      // write P to the wave's private buffer: row i_local, col jh*16+4g+r
#pragma unroll
      for (int jh = 0; jh < 2; ++jh) {
        u32 p01 = (u32)f2bf(pj[jh * 4 + 0]) | ((u32)f2bf(pj[jh * 4 + 1]) << 16);
        u32 p23 = (u32)f2bf(pj[jh * 4 + 2]) | ((u32)f2bf(pj[jh * 4 + 3]) << 16);
        *(u32*)&pbw[(it * 16 + l15) * 40 + jh * 16 + 4 * g]     = p01;
        *(u32*)&pbw[(it * 16 + l15) * 40 + jh * 16 + 4 * g + 2] = p23;
      }
    }
    // PV B-fragments from own buffer (in-order DS, no barrier):
    // pf_it[e] at lane(g,l15) = P[i=it*16+l15][j=8g+e]
    short8 pf0 = *(const short8*)&pbw[l15 * 40 + g * 8];
    short8 pf1 = *(const short8*)&pbw[(16 + l15) * 40 + g * 8];
#pragma unroll
    for (int ct = 0; ct < 4; ++ct) {
      acc[ct][0] = MFMA16(vf[ct], pf0, acc[ct][0]);
      acc[ct][1] = MFMA16(vf[ct], pf1, acc[ct][1]);
    }
  }
  // epilogue: ofT[i][c] = gamma * out/d + x1   (wave wv -> channels wv*64+..)
  float gm = gamma[0];
#pragma unroll
  for (int it = 0; it < 2; ++it) {
    float invd = 1.f / d_r[it];
    int i = i0 + it * 16 + l15;
#pragma unroll
    for (int ct = 0; ct < 4; ++ct)
#pragma unroll
      for (int r = 0; r < 4; ++r) {
        int c = wv * 64 + ct * 16 + 4 * g + r;
        size_t idx = ((size_t)b * NPIX + i) * CC + c;
        ofT[idx] = f2bf(gm * acc[ct][it][r] * invd + bf2f(x1T[idx]));
      }
  }
}

// ---------------------------------------------------------------------------
// Host launcher. Workspace layout (u16 elements unless noted):
//  xT 9437184 | x1T 4718592 | qb 1179648 | kb 1179648 | vb 4718592 |
//  ofT 4718592 | wbpre 1179648 | wbf 589824 | wqb 16384 | wkb 16384 |
//  wvb 65536 | fold (f32[1024])            total ~55.6 MB
// ---------------------------------------------------------------------------
extern "C" void kernel_launch(void* const* d_in, const int* in_sizes, int n_in,
                              void* d_out, int out_size, void* d_ws, size_t ws_size,
                              hipStream_t stream) {
  (void)in_sizes; (void)n_in; (void)out_size; (void)ws_size;
  const float* x     = (const float*)d_in[0];
  const float* w_pre = (const float*)d_in[1];
  const float* b_pre = (const float*)d_in[2];
  const float* bn1_g = (const float*)d_in[3];
  const float* bn1_b = (const float*)d_in[4];
  const float* bn1_m = (const float*)d_in[5];
  const float* bn1_v = (const float*)d_in[6];
  const float* w_q   = (const float*)d_in[7];
  const float* b_q   = (const float*)d_in[8];
  const float* w_k   = (const float*)d_in[9];
  const float* b_k   = (const float*)d_in[10];
  const float* w_v   = (const float*)d_in[11];
  const float* b_v   = (const float*)d_in[12];
  const float* w_f   = (const float*)d_in[13];
  const float* b_f   = (const float*)d_in[14];
  const float* bn2_g = (const float*)d_in[15];
  const float* bn2_b = (const float*)d_in[16];
  const float* bn2_m = (const float*)d_in[17];
  const float* bn2_v = (const float*)d_in[18];
  const float* gamma = (const float*)d_in[19];
  float* out = (float*)d_out;

  u16* wsu   = (u16*)d_ws;
  u16* xT    = wsu;
  u16* x1T   = wsu + 9437184;
  u16* qb    = wsu + 14155776;
  u16* kb    = wsu + 15335424;
  u16* vb    = wsu + 16515072;
  u16* ofT   = wsu + 21233664;
  u16* wbpre = wsu + 25952256;
  u16* wbf   = wsu + 27131904;
  u16* wqb   = wsu + 27721728;
  u16* wkb   = wsu + 27738112;
  u16* wvb   = wsu + 27754496;
  float* fold = (float*)(wsu + 27820032);

  fold_bn<<<1, 256, 0, stream>>>(b_pre, bn1_g, bn1_b, bn1_m, bn1_v,
                                 b_f, bn2_g, bn2_b, bn2_m, bn2_v, fold);
  transpose_x<<<dim3(72, 16, 8), 256, 0, stream>>>(x, xT);
  conv_w<<<7296, 256, 0, stream>>>(w_pre, w_f, w_q, w_k, w_v,
                                   wbpre, wbf, wqb, wkb, wvb);
  conv_mfma<512, true><<<dim3(48, 4, 8), 256, 0, stream>>>(
      xT, wbpre, fold, fold + 256, x1T, nullptr);
  qkv_mfma<<<dim3(72, 6, 8), 256, 0, stream>>>(
      x1T, wqb, wkb, wvb, b_q, b_k, b_v, qb, kb, vb);
  flash_mfma<<<dim3(72, 8, 1), 256, 0, stream>>>(qb, kb, vb, x1T, gamma, ofT);
  conv_mfma<256, false><<<dim3(48, 4, 8), 256, 0, stream>>>(
      ofT, wbf, fold + 512, fold + 768, nullptr, out);
}

// Round 5
// 474.325 us; speedup vs baseline: 1.4249x; 1.0805x over previous
//
#include <hip/hip_runtime.h>

// ---------------------------------------------------------------------------
// AttentionLayer (SAGAN-style) on MI355X, bf16 MFMA pipeline.
// Shapes: B=8, Cin=512, C=256, Cr=64, H=W=48, N=2304.
// Pipeline: fold BN -> transpose x -> convert weights -> conv_pre(MFMA,bf16)
//           -> qkv(MFMA) -> flash attention (split-j, MFMA, online softmax)
//           -> combine -> conv_f(MFMA) -> d_out (f32).
// R2 fix: qkv_mfma wt staging copied 4 uint4 per thread instead of 8.
// R3 fix: flash wave wv owns channel block wv*64.
// R4: barrier-free flash (403->215us).
// R5: R4 profile: flash MfmaUtil 8.4%, VALUBusy 38%, Occ 19.8% -> latency-
//     bound at 2.25 blocks/CU; VALUBusy*dur => ~82us of softmax VALU.
//     (a) split-j NSPLIT=4 (grid 72x4x8=2304 blocks) with bf16 partial-O +
//         (m,d) per row; flash_combine merges + gamma/residual.
//     (b) VALU diet: log2e folded into w_q/b_q (exp2 domain, v_exp_f32 raw),
//         defer-max theta=0 (__any wave-uniform; steady state skips rescale
//         AND shfl-max), per-lane partial d (g-reduce hoisted out of loop),
//         v_cvt_pk_bf16_f32 + ds_write_b64 for P.
// ---------------------------------------------------------------------------

typedef __attribute__((ext_vector_type(8))) short short8;   // 8 x bf16 (4 VGPR)
typedef __attribute__((ext_vector_type(4))) float f32x4;    // MFMA accumulator

#define MFMA16(A,B,C) __builtin_amdgcn_mfma_f32_16x16x32_bf16((A),(B),(C),0,0,0)

#define NB   8
#define CIN  512
#define CC   256
#define NPIX 2304
#define HWD  48
#define EPSF 1e-5f
#define NSPLIT 4
#define JT_PER 18            // 72 j-tiles / NSPLIT
#define LOG2E 1.4426950408889634f

typedef unsigned short u16;
typedef unsigned int   u32;

__device__ __forceinline__ u16 f2bf(float f) {
  union { float f; u32 u; } v; v.f = f;
  u32 r = v.u + 0x7FFFu + ((v.u >> 16) & 1u);   // round-to-nearest-even
  return (u16)(r >> 16);
}
__device__ __forceinline__ float bf2f(u16 h) {
  union { u32 u; float f; } v; v.u = ((u32)h) << 16; return v.f;
}
__device__ __forceinline__ float exp2fast(float x) {   // raw v_exp_f32 (=2^x)
  float r; asm("v_exp_f32 %0, %1" : "=v"(r) : "v"(x)); return r;
}
__device__ __forceinline__ u32 cvtpk(float lo, float hi) {  // bf16(lo)|bf16(hi)<<16
  u32 r; asm("v_cvt_pk_bf16_f32 %0, %1, %2" : "=v"(r) : "v"(lo), "v"(hi)); return r;
}

// ---------------------------------------------------------------------------
// K0: fold BN (+conv bias) into per-channel scale/shift.
// ---------------------------------------------------------------------------
__global__ void fold_bn(const float* __restrict__ b_pre,
                        const float* __restrict__ g1, const float* __restrict__ bb1,
                        const float* __restrict__ m1, const float* __restrict__ v1,
                        const float* __restrict__ b_f,
                        const float* __restrict__ g2, const float* __restrict__ bb2,
                        const float* __restrict__ m2, const float* __restrict__ v2,
                        float* __restrict__ fold) {
  int c = threadIdx.x;
  if (c < CC) {
    float inv1 = g1[c] / sqrtf(v1[c] + EPSF);
    fold[c]        = inv1;
    fold[CC + c]   = (b_pre[c] - m1[c]) * inv1 + bb1[c];
    float inv2 = g2[c] / sqrtf(v2[c] + EPSF);
    fold[2*CC + c] = inv2;
    fold[3*CC + c] = (b_f[c] - m2[c]) * inv2 + bb2[c];
  }
}

// ---------------------------------------------------------------------------
// K0b: transpose x [b][512][2304] f32 -> xT bf16 [b][2304][512]
// ---------------------------------------------------------------------------
__launch_bounds__(256)
__global__ void transpose_x(const float* __restrict__ x, u16* __restrict__ xT) {
  __shared__ u16 t[32][33];
  int tid = threadIdx.x;
  int n0 = blockIdx.x * 32, c0 = blockIdx.y * 32, b = blockIdx.z;
#pragma unroll
  for (int it = 0; it < 4; ++it) {
    int cc = (tid >> 5) + it * 8;
    int nn = tid & 31;
    t[nn][cc] = f2bf(x[((size_t)(b * CIN + c0 + cc)) * NPIX + n0 + nn]);
  }
  __syncthreads();
#pragma unroll
  for (int it = 0; it < 2; ++it) {
    int nn = (tid >> 4) + it * 16;
    int cc2 = (tid & 15) * 2;
    u32 o = (u32)t[nn][cc2] | ((u32)t[nn][cc2 + 1] << 16);
    *(u32*)&xT[((size_t)b * NPIX + n0 + nn) * CIN + c0 + cc2] = o;
  }
}

// ---------------------------------------------------------------------------
// K0c: convert/relayout weights to bf16. w_q (and its bias, at use) scaled by
// LOG2E so attention softmax runs in exp2 domain.
// ---------------------------------------------------------------------------
__launch_bounds__(256)
__global__ void conv_w(const float* __restrict__ wpre, const float* __restrict__ wf,
                       const float* __restrict__ wq, const float* __restrict__ wk,
                       const float* __restrict__ wvw,
                       u16* __restrict__ wbpre, u16* __restrict__ wbf,
                       u16* __restrict__ wqb, u16* __restrict__ wkb,
                       u16* __restrict__ wvb) {
  int idx = blockIdx.x * 256 + threadIdx.x;
  if (idx < 1179648) {                       // 9*256*512
    int tap = idx / 131072, rem = idx % 131072;
    int co = rem >> 9, ci = rem & 511;
    wbpre[idx] = f2bf(wpre[((size_t)co * CIN + ci) * 9 + tap]);
  } else if (idx < 1769472) {                // + 9*256*256
    int j = idx - 1179648;
    int tap = j / 65536, rem = j % 65536;
    int co = rem >> 8, ci = rem & 255;
    wbf[j] = f2bf(wf[((size_t)co * CC + ci) * 9 + tap]);
  } else if (idx < 1785856) {                // + 64*256
    int j = idx - 1769472; wqb[j] = f2bf(wq[j] * LOG2E);
  } else if (idx < 1802240) {                // + 64*256
    int j = idx - 1785856; wkb[j] = f2bf(wk[j]);
  } else if (idx < 1867776) {                // + 256*256
    int j = idx - 1802240; wvb[j] = f2bf(wvw[j]);
  }
}

// ---------------------------------------------------------------------------
// conv3x3 (pad 1) + BN + ReLU via implicit-GEMM MFMA.  (unchanged)
// ---------------------------------------------------------------------------
template<int CINT, bool TOUT>
__launch_bounds__(256)
__global__ void conv_mfma(const u16* __restrict__ inT, const u16* __restrict__ wb,
                          const float* __restrict__ scale, const float* __restrict__ shift,
                          u16* __restrict__ outB, float* __restrict__ outF) {
  __shared__ u16 xs[150 * 40];    // [3 rows][50 cols][ci32 pad->40]
  __shared__ u16 wsl[576 * 40];   // [9 taps][64 co][ci32 pad->40]
  int tid = threadIdx.x;
  int lane = tid & 63, wv = tid >> 6;
  int l15 = lane & 15, g = lane >> 4;
  int h = blockIdx.x, cob = blockIdx.y * 64, b = blockIdx.z;

  f32x4 z4 = {0.f, 0.f, 0.f, 0.f};
  f32x4 acc[3] = {z4, z4, z4};

#pragma unroll 1
  for (int ci0 = 0; ci0 < CINT; ci0 += 32) {
    __syncthreads();
    if (tid < 150) {
      int rr = tid / 50, col = tid % 50 - 1;
      int hh = h - 1 + rr;
      uint4 v0 = {0,0,0,0}, v1 = v0, v2 = v0, v3 = v0;
      if ((unsigned)hh < 48u && (unsigned)col < 48u) {
        const uint4* src = (const uint4*)&inT[((size_t)b * NPIX + hh * HWD + col) * CINT + ci0];
        v0 = src[0]; v1 = src[1]; v2 = src[2]; v3 = src[3];
      }
      uint4* dst = (uint4*)&xs[tid * 40];
      dst[0] = v0; dst[1] = v1; dst[2] = v2; dst[3] = v3;
    }
#pragma unroll
    for (int it = 0; it < 9; ++it) {
      int slot = tid + it * 256;
      int row = slot >> 2, q4 = slot & 3;
      int tap = row >> 6, co = row & 63;
      *((uint4*)&wsl[row * 40] + q4) =
          *(const uint4*)&wb[((size_t)(tap * 256 + cob + co)) * CINT + ci0 + q4 * 8];
    }
    __syncthreads();
#pragma unroll
    for (int kh = 0; kh < 3; ++kh) {
#pragma unroll
      for (int kw = 0; kw < 3; ++kw) {
        int tap = kh * 3 + kw;
        short8 wf = *(const short8*)&wsl[((tap * 64) + wv * 16 + l15) * 40 + g * 8];
#pragma unroll
        for (int t = 0; t < 3; ++t) {
          short8 xf = *(const short8*)&xs[(kh * 50 + t * 16 + l15 + kw) * 40 + g * 8];
          if constexpr (TOUT) acc[t] = MFMA16(xf, wf, acc[t]);   // D^T[px][co]
          else                acc[t] = MFMA16(wf, xf, acc[t]);   // D[co][px]
        }
      }
    }
  }

  if constexpr (TOUT) {
    int co = cob + wv * 16 + l15;
    float sc = scale[co], sh = shift[co];
#pragma unroll
    for (int t = 0; t < 3; ++t)
#pragma unroll
      for (int r = 0; r < 4; ++r) {
        int px = h * HWD + t * 16 + 4 * g + r;
        float v = fmaxf(fmaf(acc[t][r], sc, sh), 0.f);
        outB[((size_t)b * NPIX + px) * CC + co] = f2bf(v);
      }
  } else {
#pragma unroll
    for (int r = 0; r < 4; ++r) {
      int co = cob + wv * 16 + 4 * g + r;
      float sc = scale[co], sh = shift[co];
#pragma unroll
      for (int t = 0; t < 3; ++t) {
        int px = h * HWD + t * 16 + l15;
        float v = fmaxf(fmaf(acc[t][r], sc, sh), 0.f);
        outF[((size_t)b * CC + co) * NPIX + px] = v;
      }
    }
  }
}

// ---------------------------------------------------------------------------
// qkv 1x1 convs via MFMA. (q bias scaled by LOG2E; weights pre-scaled)
// ---------------------------------------------------------------------------
__launch_bounds__(256)
__global__ void qkv_mfma(const u16* __restrict__ x1T,
                         const u16* __restrict__ wqb, const u16* __restrict__ wkb,
                         const u16* __restrict__ wvb,
                         const float* __restrict__ b_q, const float* __restrict__ b_k,
                         const float* __restrict__ b_v,
                         u16* __restrict__ qb, u16* __restrict__ kb,
                         u16* __restrict__ vb) {
  __shared__ u16 xt[32 * 264];   // [n 32][c 256 pad->264]
  __shared__ u16 wt[64 * 264];   // [m 64][c 256 pad->264]
  int tid = threadIdx.x;
  int lane = tid & 63, wv = tid >> 6;
  int l15 = lane & 15, g = lane >> 4;
  int n0 = blockIdx.x * 32, y = blockIdx.y, b = blockIdx.z;
  const u16* w; const float* bias; int mb = 0; float bsc = 1.f;
  if (y == 0)      { w = wqb; bias = b_q; bsc = LOG2E; }
  else if (y == 1) { w = wkb; bias = b_k; }
  else             { w = wvb; bias = b_v; mb = (y - 2) * 64; }
  {
    int row = tid >> 3, s = (tid & 7) * 32;
    const uint4* src = (const uint4*)&x1T[((size_t)b * NPIX + n0 + row) * CC + s];
    uint4* dst = (uint4*)&xt[row * 264 + s];
    dst[0] = src[0]; dst[1] = src[1]; dst[2] = src[2]; dst[3] = src[3];
  }
  {
    int row = tid >> 2, s = (tid & 3) * 64;   // 64 u16 = 8 uint4 per thread
    const uint4* src = (const uint4*)&w[((size_t)(mb + row)) * CC + s];
    uint4* dst = (uint4*)&wt[row * 264 + s];
#pragma unroll
    for (int u = 0; u < 8; ++u) dst[u] = src[u];
  }
  __syncthreads();
  f32x4 z4 = {0.f, 0.f, 0.f, 0.f};
  f32x4 acc[2] = {z4, z4};
  if (y <= 1) {
#pragma unroll
    for (int cc = 0; cc < 8; ++cc) {
      short8 wf = *(const short8*)&wt[(wv * 16 + l15) * 264 + cc * 32 + g * 8];
#pragma unroll
      for (int nt = 0; nt < 2; ++nt) {
        short8 xf = *(const short8*)&xt[(nt * 16 + l15) * 264 + cc * 32 + g * 8];
        acc[nt] = MFMA16(xf, wf, acc[nt]);    // D^T[n][m]
      }
    }
    u16* outp = (y == 0) ? qb : kb;
    int m = wv * 16 + l15;
    float bi = bias[m] * bsc;
#pragma unroll
    for (int nt = 0; nt < 2; ++nt)
#pragma unroll
      for (int r = 0; r < 4; ++r) {
        int n = n0 + nt * 16 + 4 * g + r;
        outp[((size_t)b * NPIX + n) * 64 + m] = f2bf(acc[nt][r] + bi);
      }
  } else {
#pragma unroll
    for (int cc = 0; cc < 8; ++cc) {
      short8 wf = *(const short8*)&wt[(wv * 16 + l15) * 264 + cc * 32 + g * 8];
#pragma unroll
      for (int nt = 0; nt < 2; ++nt) {
        short8 xf = *(const short8*)&xt[(nt * 16 + l15) * 264 + cc * 32 + g * 8];
        acc[nt] = MFMA16(wf, xf, acc[nt]);    // D[m][n]
      }
    }
    int mrow = mb + wv * 16 + 4 * g;
#pragma unroll
    for (int r = 0; r < 4; ++r) {
      float bi = bias[mrow + r];
#pragma unroll
      for (int nt = 0; nt < 2; ++nt) {
        int n = n0 + nt * 16 + l15;
        vb[((size_t)b * CC + mrow + r) * NPIX + n] = f2bf(acc[nt][r] + bi);
      }
    }
  }
}

// ---------------------------------------------------------------------------
// Flash attention, split-j partial pass. Barrier-free; energies in exp2
// domain (q pre-scaled by LOG2E). Each block: 32 i-rows x 18 j-tiles of
// split sp. Wave wv owns channels wv*64..+63. Emits unnormalized partial
// O (bf16) and per-row (m, d) with d g-reduced at the end.
// ---------------------------------------------------------------------------
__launch_bounds__(256)
__global__ void flash_mfma(const u16* __restrict__ qbp, const u16* __restrict__ kbp,
                           const u16* __restrict__ vbp,
                           u16* __restrict__ opart, float2* __restrict__ md) {
  __shared__ u16 pb[4][32 * 40];   // per-wave private P buffer [i 32][j 32 pad->40]
  int tid = threadIdx.x;
  int lane = tid & 63, wv = tid >> 6;
  int l15 = lane & 15, g = lane >> 4;
  int i0 = blockIdx.x * 32, sp = blockIdx.y, b = blockIdx.z;
  u16* pbw = pb[wv];

  short8 qf[2][2];
#pragma unroll
  for (int it = 0; it < 2; ++it)
#pragma unroll
    for (int cc = 0; cc < 2; ++cc)
      qf[it][cc] = *(const short8*)
          &qbp[((size_t)b * NPIX + i0 + it * 16 + l15) * 64 + cc * 32 + g * 8];

  f32x4 z4 = {0.f, 0.f, 0.f, 0.f};
  f32x4 acc[4][2];
#pragma unroll
  for (int ct = 0; ct < 4; ++ct) { acc[ct][0] = z4; acc[ct][1] = z4; }
  float m_r[2] = {-1e30f, -1e30f};
  float d_l[2] = {0.f, 0.f};           // per-lane partial denominators

  const u16* kb0 = kbp + (size_t)b * NPIX * 64;
  const u16* vb0 = vbp + ((size_t)b * CC + wv * 64) * NPIX;

#pragma unroll 1
  for (int jt = 0; jt < JT_PER; ++jt) {
    int j0 = (sp * JT_PER + jt) * 32;
    short8 kf[2][2];
#pragma unroll
    for (int jh = 0; jh < 2; ++jh)
#pragma unroll
      for (int cc = 0; cc < 2; ++cc)
        kf[jh][cc] = *(const short8*)
            &kb0[(size_t)(j0 + jh * 16 + l15) * 64 + cc * 32 + g * 8];
    short8 vf[4];
#pragma unroll
    for (int ct = 0; ct < 4; ++ct)
      vf[ct] = *(const short8*)&vb0[(size_t)(ct * 16 + l15) * NPIX + j0 + g * 8];

    // QK^T (swapped): S^T[j0+jh*16+4g+r][i0+it*16+l15], exp2-domain energies
    f32x4 s[2][2];
#pragma unroll
    for (int jh = 0; jh < 2; ++jh)
#pragma unroll
      for (int it = 0; it < 2; ++it) {
        s[jh][it] = MFMA16(kf[jh][0], qf[it][0], z4);
        s[jh][it] = MFMA16(kf[jh][1], qf[it][1], s[jh][it]);
      }

    // online softmax per i-half; defer-max theta=0 (exact)
#pragma unroll
    for (int it = 0; it < 2; ++it) {
      float lmx = fmaxf(fmaxf(fmaxf(s[0][it][0], s[0][it][1]),
                              fmaxf(s[0][it][2], s[0][it][3])),
                        fmaxf(fmaxf(s[1][it][0], s[1][it][1]),
                              fmaxf(s[1][it][2], s[1][it][3])));
      if (__any(lmx > m_r[it])) {      // wave-uniform branch; rare in steady state
        float mx = lmx;
        mx = fmaxf(mx, __shfl_xor(mx, 16));
        mx = fmaxf(mx, __shfl_xor(mx, 32));
        float mnew = fmaxf(m_r[it], mx);
        float scl = exp2fast(m_r[it] - mnew);
#pragma unroll
        for (int ct = 0; ct < 4; ++ct) acc[ct][it] = acc[ct][it] * scl;
        d_l[it] *= scl;
        m_r[it] = mnew;
      }
      float m = m_r[it];
      float p[8];
      float sum = 0.f;
#pragma unroll
      for (int jh = 0; jh < 2; ++jh)
#pragma unroll
        for (int r = 0; r < 4; ++r) {
          float pv = exp2fast(s[jh][it][r] - m);
          p[jh * 4 + r] = pv; sum += pv;
        }
      d_l[it] += sum;
      // pack P into wave-private buffer: row i_local, cols jh*16+4g..+3
#pragma unroll
      for (int jh = 0; jh < 2; ++jh) {
        uint2 pk;
        pk.x = cvtpk(p[jh * 4 + 0], p[jh * 4 + 1]);
        pk.y = cvtpk(p[jh * 4 + 2], p[jh * 4 + 3]);
        *(uint2*)&pbw[(it * 16 + l15) * 40 + jh * 16 + 4 * g] = pk;
      }
    }
    // PV B-fragments from own buffer (in-order DS within wave, no barrier)
    short8 pf0 = *(const short8*)&pbw[l15 * 40 + g * 8];
    short8 pf1 = *(const short8*)&pbw[(16 + l15) * 40 + g * 8];
#pragma unroll
    for (int ct = 0; ct < 4; ++ct) {
      acc[ct][0] = MFMA16(vf[ct], pf0, acc[ct][0]);
      acc[ct][1] = MFMA16(vf[ct], pf1, acc[ct][1]);
    }
  }

  // finalize d: reduce per-lane partials across g-groups
#pragma unroll
  for (int it = 0; it < 2; ++it) {
    float d = d_l[it];
    d += __shfl_xor(d, 16);
    d += __shfl_xor(d, 32);
    d_l[it] = d;
  }
  // write partial O (unnormalized) and (m, d)
  size_t orow = (size_t)(sp * NB + b) * NPIX;
#pragma unroll
  for (int it = 0; it < 2; ++it) {
    int i = i0 + it * 16 + l15;
#pragma unroll
    for (int ct = 0; ct < 4; ++ct)
#pragma unroll
      for (int r = 0; r < 4; ++r) {
        int c = wv * 64 + ct * 16 + 4 * g + r;
        opart[(orow + i) * CC + c] = f2bf(acc[ct][it][r]);
      }
    if (wv == 0 && g == 0) md[orow + i] = make_float2(m_r[it], d_l[it]);
  }
}

// ---------------------------------------------------------------------------
// Combine NSPLIT partials: O = sum_s 2^(m_s-M) O_s / sum_s 2^(m_s-M) d_s;
// ofT[i][c] = gamma*O + x1. Block = 8 rows x 32 lanes x short8.
// ---------------------------------------------------------------------------
__launch_bounds__(256)
__global__ void flash_combine(const u16* __restrict__ opart,
                              const float2* __restrict__ md,
                              const u16* __restrict__ x1T,
                              const float* __restrict__ gamma,
                              u16* __restrict__ ofT) {
  int t = threadIdx.x;
  int i = blockIdx.x * 8 + (t >> 5);
  int b = blockIdx.y;
  int c8 = (t & 31) * 8;
  float2 mds[NSPLIT];
  float M = -1e30f;
#pragma unroll
  for (int s = 0; s < NSPLIT; ++s) {
    mds[s] = md[(size_t)(s * NB + b) * NPIX + i];
    M = fmaxf(M, mds[s].x);
  }
  float w[NSPLIT], D = 0.f;
#pragma unroll
  for (int s = 0; s < NSPLIT; ++s) {
    w[s] = exp2fast(mds[s].x - M);
    D += w[s] * mds[s].y;
  }
  float o[8];
#pragma unroll
  for (int e = 0; e < 8; ++e) o[e] = 0.f;
#pragma unroll
  for (int s = 0; s < NSPLIT; ++s) {
    short8 v = *(const short8*)&opart[((size_t)(s * NB + b) * NPIX + i) * CC + c8];
#pragma unroll
    for (int e = 0; e < 8; ++e) o[e] += w[s] * bf2f((u16)v[e]);
  }
  float gmD = gamma[0] / D;
  size_t idx = ((size_t)b * NPIX + i) * CC + c8;
  short8 x1v = *(const short8*)&x1T[idx];
  short8 out;
#pragma unroll
  for (int e = 0; e < 8; ++e)
    out[e] = (short)f2bf(o[e] * gmD + bf2f((u16)x1v[e]));
  *(short8*)&ofT[idx] = out;
}

// ---------------------------------------------------------------------------
// Host launcher. Workspace layout (u16 elements unless noted):
//  xT 9437184 | x1T 4718592 | qb 1179648 | kb 1179648 | vb 4718592 |
//  ofT 4718592 | wbpre 1179648 | wbf 589824 | wqb 16384 | wkb 16384 |
//  wvb 65536 | fold f32[1024] | opart 18874368 | md float2[73728]
//  total ~94 MB
// ---------------------------------------------------------------------------
extern "C" void kernel_launch(void* const* d_in, const int* in_sizes, int n_in,
                              void* d_out, int out_size, void* d_ws, size_t ws_size,
                              hipStream_t stream) {
  (void)in_sizes; (void)n_in; (void)out_size; (void)ws_size;
  const float* x     = (const float*)d_in[0];
  const float* w_pre = (const float*)d_in[1];
  const float* b_pre = (const float*)d_in[2];
  const float* bn1_g = (const float*)d_in[3];
  const float* bn1_b = (const float*)d_in[4];
  const float* bn1_m = (const float*)d_in[5];
  const float* bn1_v = (const float*)d_in[6];
  const float* w_q   = (const float*)d_in[7];
  const float* b_q   = (const float*)d_in[8];
  const float* w_k   = (const float*)d_in[9];
  const float* b_k   = (const float*)d_in[10];
  const float* w_v   = (const float*)d_in[11];
  const float* b_v   = (const float*)d_in[12];
  const float* w_f   = (const float*)d_in[13];
  const float* b_f   = (const float*)d_in[14];
  const float* bn2_g = (const float*)d_in[15];
  const float* bn2_b = (const float*)d_in[16];
  const float* bn2_m = (const float*)d_in[17];
  const float* bn2_v = (const float*)d_in[18];
  const float* gamma = (const float*)d_in[19];
  float* out = (float*)d_out;

  u16* wsu   = (u16*)d_ws;
  u16* xT    = wsu;
  u16* x1T   = wsu + 9437184;
  u16* qb    = wsu + 14155776;
  u16* kb    = wsu + 15335424;
  u16* vb    = wsu + 16515072;
  u16* ofT   = wsu + 21233664;
  u16* wbpre = wsu + 25952256;
  u16* wbf   = wsu + 27131904;
  u16* wqb   = wsu + 27721728;
  u16* wkb   = wsu + 27738112;
  u16* wvb   = wsu + 27754496;
  float* fold = (float*)(wsu + 27820032);
  u16* opart = wsu + 27822080;                         // NSPLIT*NB*NPIX*CC
  float2* md = (float2*)(wsu + 46696448);              // NSPLIT*NB*NPIX

  fold_bn<<<1, 256, 0, stream>>>(b_pre, bn1_g, bn1_b, bn1_m, bn1_v,
                                 b_f, bn2_g, bn2_b, bn2_m, bn2_v, fold);
  transpose_x<<<dim3(72, 16, 8), 256, 0, stream>>>(x, xT);
  conv_w<<<7296, 256, 0, stream>>>(w_pre, w_f, w_q, w_k, w_v,
                                   wbpre, wbf, wqb, wkb, wvb);
  conv_mfma<512, true><<<dim3(48, 4, 8), 256, 0, stream>>>(
      xT, wbpre, fold, fold + 256, x1T, nullptr);
  qkv_mfma<<<dim3(72, 6, 8), 256, 0, stream>>>(
      x1T, wqb, wkb, wvb, b_q, b_k, b_v, qb, kb, vb);
  flash_mfma<<<dim3(72, NSPLIT, 8), 256, 0, stream>>>(qb, kb, vb, opart, md);
  flash_combine<<<dim3(NPIX / 8, 8), 256, 0, stream>>>(opart, md, x1T, gamma, ofT);
  conv_mfma<256, false><<<dim3(48, 4, 8), 256, 0, stream>>>(
      ofT, wbf, fold + 512, fold + 768, nullptr, out);
}